// Round 5
// baseline (1020.358 us; speedup 1.0000x reference)
//
#include <hip/hip_runtime.h>
#include <hip/hip_fp16.h>
#include <stdint.h>

#define LEVELS 16
#define FEAT 2
#define TABLE_SIZE 524288
#define TMASK (TABLE_SIZE - 1)

typedef float f32x2 __attribute__((ext_vector_type(2)));
typedef float f32x4 __attribute__((ext_vector_type(4)));
typedef float f32x4u __attribute__((ext_vector_type(4), aligned(8)));  // 16B load, 8B-aligned ok

__device__ __constant__ int kRes[LEVELS] = {
    16, 22, 30, 42, 58, 80, 111, 153, 212, 294, 406, 561, 775, 1072, 1481, 2047
};

#define P1 73856093u
#define P2 19349663u
#define P3 83492791u

// Dense quad-packed (fp16) tables for levels 0..7. D = res+1.
#define NQLEV 8
#define HASH0 8
#define NHASH (LEVELS - HASH0)          // 8 hashed levels

constexpr int   cQD[NQLEV]     = { 17, 23, 31, 43, 59, 81, 112, 154 };
constexpr float cQRes[NQLEV]   = { 16.0f, 22.0f, 30.0f, 42.0f, 58.0f, 80.0f, 111.0f, 153.0f };
constexpr int   cQCum[NQLEV+1] = { 0, 4913, 17080, 46871, 126378, 331757, 863198, 2268126, 5920390 };
#define NCELLS 5920390                   // total cells across levels 0..7

// ---------------- remap stage 1: hashed tables -> dense f32 [D^3] cells ----------------
__global__ __launch_bounds__(256) void remap1_kernel(
    const float* __restrict__ tables,
    f32x2* __restrict__ dense)           // [NCELLS] (aliases hashed-staging region; dead after remap2)
{
    const int d = blockIdx.x * 256 + threadIdx.x;
    if (d >= NCELLS) return;
    int l = 0;
#pragma unroll
    for (int k = 1; k < NQLEV; ++k)
        if (d >= cQCum[k]) l = k;
    const int D   = cQD[l];
    const int rel = d - cQCum[l];
    const uint32_t bx = rel / (D * D);
    const uint32_t r  = rel - bx * (D * D);
    const uint32_t by = r / D;
    const uint32_t bz = r - by * D;
    const uint32_t slot = ((bx * P1) ^ (by * P2) ^ (bz * P3)) & TMASK;
    const f32x2* __restrict__ tab = reinterpret_cast<const f32x2*>(tables) + (size_t)l * TABLE_SIZE;
    dense[d] = tab[slot];
}

// ---------------- remap stage 2: f32 cells -> fp16 2x2 (y,z) quads, 16B each ----------------
// quad[d] = {c(x,y,z), c(x,y,z+1), c(x,y+1,z), c(x,y+1,z+1)} as 4x half2.
// Quads at y==D-1 / z==D-1 are never read (base coords <= D-2); their overread stays inside
// the (much larger) staging region that stage-1 aliases.
__global__ __launch_bounds__(256) void remap2_kernel(
    const f32x2* __restrict__ dense,
    uint4* __restrict__ qtab)            // [NCELLS]
{
    const int d = blockIdx.x * 256 + threadIdx.x;
    if (d >= NCELLS) return;
    int l = 0;
#pragma unroll
    for (int k = 1; k < NQLEV; ++k)
        if (d >= cQCum[k]) l = k;
    const int D   = cQD[l];
    const int rel = d - cQCum[l];

    const f32x2* __restrict__ dl = dense + cQCum[l];
    const f32x4u a = *reinterpret_cast<const f32x4u*>(dl + rel);          // (y ,z),(y ,z+1)
    const f32x4u b = *reinterpret_cast<const f32x4u*>(dl + rel + D);      // (y+1,z),(y+1,z+1)

    union { __half2 h; uint32_t u; } p0, p1, p2, p3;
    p0.h = __float22half2_rn(make_float2(a.x, a.y));
    p1.h = __float22half2_rn(make_float2(a.z, a.w));
    p2.h = __float22half2_rn(make_float2(b.x, b.y));
    p3.h = __float22half2_rn(make_float2(b.z, b.w));
    qtab[d] = make_uint4(p0.u, p1.u, p2.u, p3.u);
}

// ---------------- hashed levels l0..15: proven structure (2 pts/thread, 75us/level) ----------------
__global__ __launch_bounds__(256) void encode_level_kernel(
    const float* __restrict__ x,
    const float* __restrict__ tables,
    f32x2* __restrict__ ws,              // staging: level l stored at ws + (l-l0)*n
    int n, int nb, int l0)
{
    const int l   = l0 + blockIdx.x / nb;
    const int blk = blockIdx.x - (l - l0) * nb;
    const int t   = threadIdx.x;
    const int p0  = blk * 512;

    __shared__ float sx[512 * 3];
    const long long total3 = (long long)n * 3;
    const long long gbase  = (long long)p0 * 3;
#pragma unroll
    for (int k = 0; k < 6; ++k) {
        long long g = gbase + k * 256 + t;
        sx[k * 256 + t] = (g < total3) ? __builtin_nontemporal_load(x + g) : 0.0f;
    }
    __syncthreads();

    const float resf = (float)kRes[l];
    const f32x2* __restrict__ tab = reinterpret_cast<const f32x2*>(tables) + (size_t)l * TABLE_SIZE;

    uint32_t idx[2][8];
    float    wgt[2][8];
#pragma unroll
    for (int s = 0; s < 2; ++s) {
        const int tp = s * 256 + t;
        const float fx = sx[3 * tp + 0] * resf;
        const float fy = sx[3 * tp + 1] * resf;
        const float fz = sx[3 * tp + 2] * resf;
        const float flx = floorf(fx), fly = floorf(fy), flz = floorf(fz);
        const float wx = fx - flx, wy = fy - fly, wz = fz - flz;
        const float ux = 1.0f - wx, uy = 1.0f - wy, uz = 1.0f - wz;
        const uint32_t hx0 = (uint32_t)(int)flx * P1, hx1 = hx0 + P1;
        const uint32_t hy0 = (uint32_t)(int)fly * P2, hy1 = hy0 + P2;
        const uint32_t hz0 = (uint32_t)(int)flz * P3, hz1 = hz0 + P3;
#pragma unroll
        for (int c = 0; c < 8; ++c) {
            const uint32_t hx = (c & 4) ? hx1 : hx0;
            const uint32_t hy = (c & 2) ? hy1 : hy0;
            const uint32_t hz = (c & 1) ? hz1 : hz0;
            idx[s][c] = (hx ^ hy ^ hz) & TMASK;
            wgt[s][c] = ((c & 4) ? wx : ux) * ((c & 2) ? wy : uy) * ((c & 1) ? wz : uz);
        }
    }

    f32x2 v[2][8];
#pragma unroll
    for (int s = 0; s < 2; ++s)
#pragma unroll
        for (int c = 0; c < 8; ++c)
            v[s][c] = tab[idx[s][c]];

#pragma unroll
    for (int s = 0; s < 2; ++s) {
        float f0 = 0.0f, f1 = 0.0f;
#pragma unroll
        for (int c = 0; c < 8; ++c) {
            f0 = fmaf(wgt[s][c], v[s][c].x, f0);
            f1 = fmaf(wgt[s][c], v[s][c].y, f1);
        }
        const int i = p0 + s * 256 + t;
        if (i < n) {
            f32x2 r; r.x = f0; r.y = f1;
            __builtin_nontemporal_store(r, ws + (size_t)(l - l0) * n + i);
        }
    }
}

// ---------------- finalize: 8 fp16-quad dense levels (2 req/pt/level) + hashed ws + out ----------------
__global__ __launch_bounds__(256) void finalize_kernel(
    const float* __restrict__ x,
    const uint4* __restrict__ qtab,
    const f32x2* __restrict__ ws,        // hashed staging, level 8+j at ws + j*n
    float* __restrict__ out,
    int n)
{
    __shared__ float s[256 * 33];
    __shared__ float sx[256 * 3];
    const int t  = threadIdx.x;
    const int p0 = blockIdx.x * 256;
    const int m  = min(256, n - p0);

    const long long total3 = (long long)n * 3;
    const long long gbase  = (long long)p0 * 3;
#pragma unroll
    for (int k = 0; k < 3; ++k) {
        long long g = gbase + k * 256 + t;
        sx[k * 256 + t] = (g < total3) ? __builtin_nontemporal_load(x + g) : 0.0f;
    }
    __syncthreads();

    if (t < m) {
        const int i = p0 + t;

        // hashed results: coalesced 8B loads, issued early
        f32x2 h[NHASH];
#pragma unroll
        for (int j = 0; j < NHASH; ++j)
            h[j] = __builtin_nontemporal_load(ws + (size_t)j * n + i);

        const float px = sx[3 * t + 0];
        const float py = sx[3 * t + 1];
        const float pz = sx[3 * t + 2];

#pragma unroll
        for (int l = 0; l < NQLEV; ++l) {
            const int   D    = cQD[l];
            const int   DD   = D * D;
            const float resf = cQRes[l];
            const uint4* __restrict__ qt = qtab + cQCum[l];

            const float fx = px * resf, fy = py * resf, fz = pz * resf;
            const float flx = floorf(fx), fly = floorf(fy), flz = floorf(fz);
            const float wx = fx - flx, wy = fy - fly, wz = fz - flz;
            const float ux = 1.0f - wx, uy = 1.0f - wy, uz = 1.0f - wz;
            const int q0 = (((int)flx * D + (int)fly) * D + (int)flz);

            const uint4 A = qt[q0];        // x = bx  : (y,z),(y,z+1),(y+1,z),(y+1,z+1)
            const uint4 B = qt[q0 + DD];   // x = bx+1

            union { uint32_t u; __half2 hh; } c;
            float2 a00, a01, a10, a11, b00, b01, b10, b11;
            c.u = A.x; a00 = __half22float2(c.hh);
            c.u = A.y; a01 = __half22float2(c.hh);
            c.u = A.z; a10 = __half22float2(c.hh);
            c.u = A.w; a11 = __half22float2(c.hh);
            c.u = B.x; b00 = __half22float2(c.hh);
            c.u = B.y; b01 = __half22float2(c.hh);
            c.u = B.z; b10 = __half22float2(c.hh);
            c.u = B.w; b11 = __half22float2(c.hh);

            const float ya0 = fmaf(uz, a00.x, wz * a01.x), ya1 = fmaf(uz, a10.x, wz * a11.x);
            const float yb0 = fmaf(uz, b00.x, wz * b01.x), yb1 = fmaf(uz, b10.x, wz * b11.x);
            const float f0  = fmaf(ux, fmaf(uy, ya0, wy * ya1), wx * fmaf(uy, yb0, wy * yb1));
            const float za0 = fmaf(uz, a00.y, wz * a01.y), za1 = fmaf(uz, a10.y, wz * a11.y);
            const float zb0 = fmaf(uz, b00.y, wz * b01.y), zb1 = fmaf(uz, b10.y, wz * b11.y);
            const float f1  = fmaf(ux, fmaf(uy, za0, wy * za1), wx * fmaf(uy, zb0, wy * zb1));

            s[t * 33 + 2 * l + 0] = f0;
            s[t * 33 + 2 * l + 1] = f1;
        }
#pragma unroll
        for (int j = 0; j < NHASH; ++j) {
            s[t * 33 + 2 * (NQLEV + j) + 0] = h[j].x;
            s[t * 33 + 2 * (NQLEV + j) + 1] = h[j].y;
        }
    }
    __syncthreads();

    const int nchunk = m * 8;
    f32x4* __restrict__ o4 = reinterpret_cast<f32x4*>(out) + (size_t)p0 * 8;
#pragma unroll
    for (int j = 0; j < 8; ++j) {
        const int cl = j * 256 + t;
        if (cl < nchunk) {
            const int p = cl >> 3, ch = cl & 7;
            f32x4 q;
            q.x = s[p * 33 + ch * 4 + 0];
            q.y = s[p * 33 + ch * 4 + 1];
            q.z = s[p * 33 + ch * 4 + 2];
            q.w = s[p * 33 + ch * 4 + 3];
            __builtin_nontemporal_store(q, o4 + cl);
        }
    }
}

// ---------------- fallback: fused single-kernel path (if ws too small) ----------------
__global__ __launch_bounds__(256) void hashgrid_enc_kernel(
    const float* __restrict__ x,
    const float* __restrict__ tables,
    float* __restrict__ out,
    int n)
{
    __shared__ float sx[256 * 3];
    const int t = threadIdx.x;
    const int block0 = blockIdx.x * 256;
    const long long total3 = (long long)n * 3;
    const long long gbase = (long long)block0 * 3;
#pragma unroll
    for (int k = 0; k < 3; ++k) {
        long long g = gbase + k * 256 + t;
        sx[k * 256 + t] = (g < total3) ? x[g] : 0.0f;
    }
    __syncthreads();
    const int i = block0 + t;
    if (i >= n) return;
    const float px = sx[3 * t + 0];
    const float py = sx[3 * t + 1];
    const float pz = sx[3 * t + 2];
    float outv[2 * LEVELS];
#pragma unroll
    for (int l = 0; l < LEVELS; ++l) {
        const float resf = (float)kRes[l];
        const float fx = px * resf, fy = py * resf, fz = pz * resf;
        const float flx = floorf(fx), fly = floorf(fy), flz = floorf(fz);
        const float wx = fx - flx, wy = fy - fly, wz = fz - flz;
        const float ux = 1.0f - wx, uy = 1.0f - wy, uz = 1.0f - wz;
        const uint32_t hx0 = (uint32_t)(int)flx * P1, hx1 = hx0 + P1;
        const uint32_t hy0 = (uint32_t)(int)fly * P2, hy1 = hy0 + P2;
        const uint32_t hz0 = (uint32_t)(int)flz * P3, hz1 = hz0 + P3;
        const float* __restrict__ tab = tables + (size_t)l * (TABLE_SIZE * FEAT);
        float f0 = 0.0f, f1 = 0.0f;
#pragma unroll
        for (int c = 0; c < 8; ++c) {
            const uint32_t hx = (c & 4) ? hx1 : hx0;
            const uint32_t hy = (c & 2) ? hy1 : hy0;
            const uint32_t hz = (c & 1) ? hz1 : hz0;
            const uint32_t idx = (hx ^ hy ^ hz) & TMASK;
            const float2 v = *reinterpret_cast<const float2*>(tab + (size_t)idx * FEAT);
            const float w = ((c & 4) ? wx : ux) * ((c & 2) ? wy : uy) * ((c & 1) ? wz : uz);
            f0 = fmaf(w, v.x, f0);
            f1 = fmaf(w, v.y, f1);
        }
        outv[2 * l + 0] = f0;
        outv[2 * l + 1] = f1;
    }
    float4* __restrict__ o4 = reinterpret_cast<float4*>(out + (size_t)i * (2 * LEVELS));
#pragma unroll
    for (int k = 0; k < 8; ++k) {
        o4[k] = make_float4(outv[4 * k + 0], outv[4 * k + 1],
                            outv[4 * k + 2], outv[4 * k + 3]);
    }
}

extern "C" void kernel_launch(void* const* d_in, const int* in_sizes, int n_in,
                              void* d_out, int out_size, void* d_ws, size_t ws_size,
                              hipStream_t stream) {
    const float* x = (const float*)d_in[0];
    const float* tables = (const float*)d_in[1];
    float* out = (float*)d_out;
    const int n = in_sizes[0] / 3;

    // ws layout:
    //   [region R0: max(hashed staging NHASH*n*8B, stage-1 f32 cells NCELLS*8B)] [qtab: NCELLS*16B]
    // stage-1 aliases the staging region: remap1/remap2 complete (stream-ordered) before
    // encode_level overwrites R0 with staging data.
    const size_t stag_b = (size_t)NHASH * (size_t)n * sizeof(f32x2);
    const size_t s1_b   = ((size_t)NCELLS + 256) * sizeof(f32x2);   // + remap2 row-overread slack
    const size_t r0_b   = (stag_b > s1_b ? stag_b : s1_b);
    const size_t qoff   = (r0_b + 15) & ~(size_t)15;
    const size_t need   = qoff + (size_t)NCELLS * sizeof(uint4);

    if (ws_size >= need) {
        f32x2* staging = (f32x2*)d_ws;
        f32x2* stage1  = (f32x2*)d_ws;
        uint4* qtab    = (uint4*)((char*)d_ws + qoff);

        const int nbcell = (NCELLS + 255) / 256;
        hipLaunchKernelGGL(remap1_kernel, dim3(nbcell), dim3(256), 0, stream, tables, stage1);
        hipLaunchKernelGGL(remap2_kernel, dim3(nbcell), dim3(256), 0, stream, stage1, qtab);

        const int nb512 = (n + 511) / 512;
        hipLaunchKernelGGL(encode_level_kernel, dim3(nb512 * NHASH), dim3(256), 0, stream,
                           x, tables, staging, n, nb512, HASH0);

        const int nb256 = (n + 255) / 256;
        hipLaunchKernelGGL(finalize_kernel, dim3(nb256), dim3(256), 0, stream,
                           x, qtab, staging, out, n);
    } else {
        const int nb = (n + 255) / 256;
        hipLaunchKernelGGL(hashgrid_enc_kernel, dim3(nb), dim3(256), 0, stream,
                           x, tables, out, n);
    }
}

// Round 6
// 970.868 us; speedup vs baseline: 1.0510x; 1.0510x over previous
//
#include <hip/hip_runtime.h>
#include <hip/hip_fp16.h>
#include <stdint.h>

#define LEVELS 16
#define FEAT 2
#define TABLE_SIZE 524288
#define TMASK (TABLE_SIZE - 1)

typedef float f32x2 __attribute__((ext_vector_type(2)));
typedef float f32x4 __attribute__((ext_vector_type(4)));
typedef float f32x4u __attribute__((ext_vector_type(4), aligned(8)));  // 16B load, 8B-aligned ok

__device__ __constant__ int kRes[LEVELS] = {
    16, 22, 30, 42, 58, 80, 111, 153, 212, 294, 406, 561, 775, 1072, 1481, 2047
};

#define P1 73856093u
#define P2 19349663u
#define P3 83492791u

// Quad-packed (fp16) dense tables for levels 0..6. D = res+1.
#define NQ 7
#define HASH0 7
#define NHASH (LEVELS - HASH0)          // 9 hashed levels (7..15)
#define NSTAGE (LEVELS - 5)             // 11 staged levels (5..15), slot = level-5
#define NFIN 5                          // finalize-local dense levels 0..4 (L2-resident)

constexpr int   cQD[NQ]     = { 17, 23, 31, 43, 59, 81, 112 };
constexpr float cQRes[NQ]   = { 16.0f, 22.0f, 30.0f, 42.0f, 58.0f, 80.0f, 111.0f };
constexpr int   cQCum[NQ+1] = { 0, 4913, 17080, 46871, 126378, 331757, 863198, 2268126 };
#define NCELLS 2268126                   // total cells across levels 0..6

// ---------------- remap stage 1: hashed tables -> dense f32 [D^3] cells ----------------
__global__ __launch_bounds__(256) void remap1_kernel(
    const float* __restrict__ tables,
    f32x2* __restrict__ dense)           // [NCELLS] (aliases staging region; dead after remap2)
{
    const int d = blockIdx.x * 256 + threadIdx.x;
    if (d >= NCELLS) return;
    int l = 0;
#pragma unroll
    for (int k = 1; k < NQ; ++k)
        if (d >= cQCum[k]) l = k;
    const int D   = cQD[l];
    const int rel = d - cQCum[l];
    const uint32_t bx = rel / (D * D);
    const uint32_t r  = rel - bx * (D * D);
    const uint32_t by = r / D;
    const uint32_t bz = r - by * D;
    const uint32_t slot = ((bx * P1) ^ (by * P2) ^ (bz * P3)) & TMASK;
    const f32x2* __restrict__ tab = reinterpret_cast<const f32x2*>(tables) + (size_t)l * TABLE_SIZE;
    dense[d] = tab[slot];
}

// ---------------- remap stage 2: f32 cells -> fp16 2x2 (y,z) quads, 16B each ----------------
// quad[d] = {c(x,y,z), c(x,y,z+1), c(x,y+1,z), c(x,y+1,z+1)} as 4x half2.
// Quads at y==D-1 / z==D-1 are never read (base coords <= D-2); their overread stays inside
// the (much larger) staging region that stage-1 aliases.
__global__ __launch_bounds__(256) void remap2_kernel(
    const f32x2* __restrict__ dense,
    uint4* __restrict__ qtab)            // [NCELLS]
{
    const int d = blockIdx.x * 256 + threadIdx.x;
    if (d >= NCELLS) return;
    int l = 0;
#pragma unroll
    for (int k = 1; k < NQ; ++k)
        if (d >= cQCum[k]) l = k;
    const int D   = cQD[l];
    const int rel = d - cQCum[l];

    const f32x2* __restrict__ dl = dense + cQCum[l];
    const f32x4u a = *reinterpret_cast<const f32x4u*>(dl + rel);          // (y ,z),(y ,z+1)
    const f32x4u b = *reinterpret_cast<const f32x4u*>(dl + rel + D);      // (y+1,z),(y+1,z+1)

    union { __half2 h; uint32_t u; } p0, p1, p2, p3;
    p0.h = __float22half2_rn(make_float2(a.x, a.y));
    p1.h = __float22half2_rn(make_float2(a.z, a.w));
    p2.h = __float22half2_rn(make_float2(b.x, b.y));
    p3.h = __float22half2_rn(make_float2(b.z, b.w));
    qtab[d] = make_uint4(p0.u, p1.u, p2.u, p3.u);
}

// ---------------- hashed levels 7..15: proven structure (2 pts/thread, 75us/level) ----------------
__global__ __launch_bounds__(256) void encode_level_kernel(
    const float* __restrict__ x,
    const float* __restrict__ tables,
    f32x2* __restrict__ ws,              // staging: level l stored at ws + (l-5)*n
    int n, int nb, int l0)
{
    const int l   = l0 + blockIdx.x / nb;
    const int blk = blockIdx.x - (l - l0) * nb;
    const int t   = threadIdx.x;
    const int p0  = blk * 512;

    __shared__ float sx[512 * 3];
    const long long total3 = (long long)n * 3;
    const long long gbase  = (long long)p0 * 3;
#pragma unroll
    for (int k = 0; k < 6; ++k) {
        long long g = gbase + k * 256 + t;
        sx[k * 256 + t] = (g < total3) ? __builtin_nontemporal_load(x + g) : 0.0f;
    }
    __syncthreads();

    const float resf = (float)kRes[l];
    const f32x2* __restrict__ tab = reinterpret_cast<const f32x2*>(tables) + (size_t)l * TABLE_SIZE;

    uint32_t idx[2][8];
    float    wgt[2][8];
#pragma unroll
    for (int s = 0; s < 2; ++s) {
        const int tp = s * 256 + t;
        const float fx = sx[3 * tp + 0] * resf;
        const float fy = sx[3 * tp + 1] * resf;
        const float fz = sx[3 * tp + 2] * resf;
        const float flx = floorf(fx), fly = floorf(fy), flz = floorf(fz);
        const float wx = fx - flx, wy = fy - fly, wz = fz - flz;
        const float ux = 1.0f - wx, uy = 1.0f - wy, uz = 1.0f - wz;
        const uint32_t hx0 = (uint32_t)(int)flx * P1, hx1 = hx0 + P1;
        const uint32_t hy0 = (uint32_t)(int)fly * P2, hy1 = hy0 + P2;
        const uint32_t hz0 = (uint32_t)(int)flz * P3, hz1 = hz0 + P3;
#pragma unroll
        for (int c = 0; c < 8; ++c) {
            const uint32_t hx = (c & 4) ? hx1 : hx0;
            const uint32_t hy = (c & 2) ? hy1 : hy0;
            const uint32_t hz = (c & 1) ? hz1 : hz0;
            idx[s][c] = (hx ^ hy ^ hz) & TMASK;
            wgt[s][c] = ((c & 4) ? wx : ux) * ((c & 2) ? wy : uy) * ((c & 1) ? wz : uz);
        }
    }

    f32x2 v[2][8];
#pragma unroll
    for (int s = 0; s < 2; ++s)
#pragma unroll
        for (int c = 0; c < 8; ++c)
            v[s][c] = tab[idx[s][c]];

#pragma unroll
    for (int s = 0; s < 2; ++s) {
        float f0 = 0.0f, f1 = 0.0f;
#pragma unroll
        for (int c = 0; c < 8; ++c) {
            f0 = fmaf(wgt[s][c], v[s][c].x, f0);
            f1 = fmaf(wgt[s][c], v[s][c].y, f1);
        }
        const int i = p0 + s * 256 + t;
        if (i < n) {
            f32x2 r; r.x = f0; r.y = f1;
            __builtin_nontemporal_store(r, ws + (size_t)(l - 5) * n + i);
        }
    }
}

// ---------------- dense levels 5,6 from fp16 quads: high-MLP staged structure ----------------
__global__ __launch_bounds__(256) void encode_dense56_kernel(
    const float* __restrict__ x,
    const uint4* __restrict__ qtab,
    f32x2* __restrict__ ws,              // slots 0,1 (levels 5,6)
    int n, int nb)
{
    const int lsel = blockIdx.x / nb;    // 0 -> level 5, 1 -> level 6
    const int blk  = blockIdx.x - lsel * nb;
    const int t    = threadIdx.x;
    const int p0   = blk * 512;

    __shared__ float sx[512 * 3];
    const long long total3 = (long long)n * 3;
    const long long gbase  = (long long)p0 * 3;
#pragma unroll
    for (int k = 0; k < 6; ++k) {
        long long g = gbase + k * 256 + t;
        sx[k * 256 + t] = (g < total3) ? __builtin_nontemporal_load(x + g) : 0.0f;
    }
    __syncthreads();

    const int   D    = lsel ? 112 : 81;
    const int   DD   = D * D;
    const float resf = lsel ? 111.0f : 80.0f;
    const uint4* __restrict__ qt = qtab + (lsel ? cQCum[6] : cQCum[5]);

    int   q0a[2];
    float wxa[2], wya[2], wza[2];
#pragma unroll
    for (int s = 0; s < 2; ++s) {
        const int tp = s * 256 + t;
        const float fx = sx[3 * tp + 0] * resf;
        const float fy = sx[3 * tp + 1] * resf;
        const float fz = sx[3 * tp + 2] * resf;
        const float flx = floorf(fx), fly = floorf(fy), flz = floorf(fz);
        wxa[s] = fx - flx; wya[s] = fy - fly; wza[s] = fz - flz;
        q0a[s] = ((int)flx * D + (int)fly) * D + (int)flz;
    }

    // 4 quad-loads in flight per thread
    uint4 A[2], B[2];
#pragma unroll
    for (int s = 0; s < 2; ++s) {
        A[s] = qt[q0a[s]];
        B[s] = qt[q0a[s] + DD];
    }

#pragma unroll
    for (int s = 0; s < 2; ++s) {
        const float wx = wxa[s], wy = wya[s], wz = wza[s];
        const float ux = 1.0f - wx, uy = 1.0f - wy, uz = 1.0f - wz;

        union { uint32_t u; __half2 hh; } c;
        float2 a00, a01, a10, a11, b00, b01, b10, b11;
        c.u = A[s].x; a00 = __half22float2(c.hh);
        c.u = A[s].y; a01 = __half22float2(c.hh);
        c.u = A[s].z; a10 = __half22float2(c.hh);
        c.u = A[s].w; a11 = __half22float2(c.hh);
        c.u = B[s].x; b00 = __half22float2(c.hh);
        c.u = B[s].y; b01 = __half22float2(c.hh);
        c.u = B[s].z; b10 = __half22float2(c.hh);
        c.u = B[s].w; b11 = __half22float2(c.hh);

        const float ya0 = fmaf(uz, a00.x, wz * a01.x), ya1 = fmaf(uz, a10.x, wz * a11.x);
        const float yb0 = fmaf(uz, b00.x, wz * b01.x), yb1 = fmaf(uz, b10.x, wz * b11.x);
        const float f0  = fmaf(ux, fmaf(uy, ya0, wy * ya1), wx * fmaf(uy, yb0, wy * yb1));
        const float za0 = fmaf(uz, a00.y, wz * a01.y), za1 = fmaf(uz, a10.y, wz * a11.y);
        const float zb0 = fmaf(uz, b00.y, wz * b01.y), zb1 = fmaf(uz, b10.y, wz * b11.y);
        const float f1  = fmaf(ux, fmaf(uy, za0, wy * za1), wx * fmaf(uy, zb0, wy * zb1));

        const int i = p0 + s * 256 + t;
        if (i < n) {
            f32x2 r; r.x = f0; r.y = f1;
            __builtin_nontemporal_store(r, ws + (size_t)lsel * n + i);
        }
    }
}

// ---------------- finalize: 5 L2-resident quad levels + 11 staged levels + out ----------------
__global__ __launch_bounds__(256) void finalize_kernel(
    const float* __restrict__ x,
    const uint4* __restrict__ qtab,
    const f32x2* __restrict__ ws,        // staged, level 5+j at ws + j*n
    float* __restrict__ out,
    int n)
{
    __shared__ float s[256 * 33];
    __shared__ float sx[256 * 3];
    const int t  = threadIdx.x;
    const int p0 = blockIdx.x * 256;
    const int m  = min(256, n - p0);

    const long long total3 = (long long)n * 3;
    const long long gbase  = (long long)p0 * 3;
#pragma unroll
    for (int k = 0; k < 3; ++k) {
        long long g = gbase + k * 256 + t;
        sx[k * 256 + t] = (g < total3) ? __builtin_nontemporal_load(x + g) : 0.0f;
    }
    __syncthreads();

    if (t < m) {
        const int i = p0 + t;

        // staged results: coalesced 8B loads, issued early
        f32x2 h[NSTAGE];
#pragma unroll
        for (int j = 0; j < NSTAGE; ++j)
            h[j] = __builtin_nontemporal_load(ws + (size_t)j * n + i);

        const float px = sx[3 * t + 0];
        const float py = sx[3 * t + 1];
        const float pz = sx[3 * t + 2];

#pragma unroll
        for (int l = 0; l < NFIN; ++l) {
            const int   D    = cQD[l];
            const int   DD   = D * D;
            const float resf = cQRes[l];
            const uint4* __restrict__ qt = qtab + cQCum[l];

            const float fx = px * resf, fy = py * resf, fz = pz * resf;
            const float flx = floorf(fx), fly = floorf(fy), flz = floorf(fz);
            const float wx = fx - flx, wy = fy - fly, wz = fz - flz;
            const float ux = 1.0f - wx, uy = 1.0f - wy, uz = 1.0f - wz;
            const int q0 = (((int)flx * D + (int)fly) * D + (int)flz);

            const uint4 A = qt[q0];        // x = bx  : (y,z),(y,z+1),(y+1,z),(y+1,z+1)
            const uint4 B = qt[q0 + DD];   // x = bx+1

            union { uint32_t u; __half2 hh; } c;
            float2 a00, a01, a10, a11, b00, b01, b10, b11;
            c.u = A.x; a00 = __half22float2(c.hh);
            c.u = A.y; a01 = __half22float2(c.hh);
            c.u = A.z; a10 = __half22float2(c.hh);
            c.u = A.w; a11 = __half22float2(c.hh);
            c.u = B.x; b00 = __half22float2(c.hh);
            c.u = B.y; b01 = __half22float2(c.hh);
            c.u = B.z; b10 = __half22float2(c.hh);
            c.u = B.w; b11 = __half22float2(c.hh);

            const float ya0 = fmaf(uz, a00.x, wz * a01.x), ya1 = fmaf(uz, a10.x, wz * a11.x);
            const float yb0 = fmaf(uz, b00.x, wz * b01.x), yb1 = fmaf(uz, b10.x, wz * b11.x);
            const float f0  = fmaf(ux, fmaf(uy, ya0, wy * ya1), wx * fmaf(uy, yb0, wy * yb1));
            const float za0 = fmaf(uz, a00.y, wz * a01.y), za1 = fmaf(uz, a10.y, wz * a11.y);
            const float zb0 = fmaf(uz, b00.y, wz * b01.y), zb1 = fmaf(uz, b10.y, wz * b11.y);
            const float f1  = fmaf(ux, fmaf(uy, za0, wy * za1), wx * fmaf(uy, zb0, wy * zb1));

            s[t * 33 + 2 * l + 0] = f0;
            s[t * 33 + 2 * l + 1] = f1;
        }
#pragma unroll
        for (int j = 0; j < NSTAGE; ++j) {
            s[t * 33 + 2 * (NFIN + j) + 0] = h[j].x;
            s[t * 33 + 2 * (NFIN + j) + 1] = h[j].y;
        }
    }
    __syncthreads();

    const int nchunk = m * 8;
    f32x4* __restrict__ o4 = reinterpret_cast<f32x4*>(out) + (size_t)p0 * 8;
#pragma unroll
    for (int j = 0; j < 8; ++j) {
        const int cl = j * 256 + t;
        if (cl < nchunk) {
            const int p = cl >> 3, ch = cl & 7;
            f32x4 q;
            q.x = s[p * 33 + ch * 4 + 0];
            q.y = s[p * 33 + ch * 4 + 1];
            q.z = s[p * 33 + ch * 4 + 2];
            q.w = s[p * 33 + ch * 4 + 3];
            __builtin_nontemporal_store(q, o4 + cl);
        }
    }
}

// ---------------- fallback: fused single-kernel path (if ws too small) ----------------
__global__ __launch_bounds__(256) void hashgrid_enc_kernel(
    const float* __restrict__ x,
    const float* __restrict__ tables,
    float* __restrict__ out,
    int n)
{
    __shared__ float sx[256 * 3];
    const int t = threadIdx.x;
    const int block0 = blockIdx.x * 256;
    const long long total3 = (long long)n * 3;
    const long long gbase = (long long)block0 * 3;
#pragma unroll
    for (int k = 0; k < 3; ++k) {
        long long g = gbase + k * 256 + t;
        sx[k * 256 + t] = (g < total3) ? x[g] : 0.0f;
    }
    __syncthreads();
    const int i = block0 + t;
    if (i >= n) return;
    const float px = sx[3 * t + 0];
    const float py = sx[3 * t + 1];
    const float pz = sx[3 * t + 2];
    float outv[2 * LEVELS];
#pragma unroll
    for (int l = 0; l < LEVELS; ++l) {
        const float resf = (float)kRes[l];
        const float fx = px * resf, fy = py * resf, fz = pz * resf;
        const float flx = floorf(fx), fly = floorf(fy), flz = floorf(fz);
        const float wx = fx - flx, wy = fy - fly, wz = fz - flz;
        const float ux = 1.0f - wx, uy = 1.0f - wy, uz = 1.0f - wz;
        const uint32_t hx0 = (uint32_t)(int)flx * P1, hx1 = hx0 + P1;
        const uint32_t hy0 = (uint32_t)(int)fly * P2, hy1 = hy0 + P2;
        const uint32_t hz0 = (uint32_t)(int)flz * P3, hz1 = hz0 + P3;
        const float* __restrict__ tab = tables + (size_t)l * (TABLE_SIZE * FEAT);
        float f0 = 0.0f, f1 = 0.0f;
#pragma unroll
        for (int c = 0; c < 8; ++c) {
            const uint32_t hx = (c & 4) ? hx1 : hx0;
            const uint32_t hy = (c & 2) ? hy1 : hy0;
            const uint32_t hz = (c & 1) ? hz1 : hz0;
            const uint32_t idx = (hx ^ hy ^ hz) & TMASK;
            const float2 v = *reinterpret_cast<const float2*>(tab + (size_t)idx * FEAT);
            const float w = ((c & 4) ? wx : ux) * ((c & 2) ? wy : uy) * ((c & 1) ? wz : uz);
            f0 = fmaf(w, v.x, f0);
            f1 = fmaf(w, v.y, f1);
        }
        outv[2 * l + 0] = f0;
        outv[2 * l + 1] = f1;
    }
    float4* __restrict__ o4 = reinterpret_cast<float4*>(out + (size_t)i * (2 * LEVELS));
#pragma unroll
    for (int k = 0; k < 8; ++k) {
        o4[k] = make_float4(outv[4 * k + 0], outv[4 * k + 1],
                            outv[4 * k + 2], outv[4 * k + 3]);
    }
}

extern "C" void kernel_launch(void* const* d_in, const int* in_sizes, int n_in,
                              void* d_out, int out_size, void* d_ws, size_t ws_size,
                              hipStream_t stream) {
    const float* x = (const float*)d_in[0];
    const float* tables = (const float*)d_in[1];
    float* out = (float*)d_out;
    const int n = in_sizes[0] / 3;

    // ws layout:
    //   [region R0: max(staging NSTAGE*n*8B, stage-1 f32 cells (NCELLS+slack)*8B)] [qtab: NCELLS*16B]
    // stage-1 aliases the staging region: remap1/remap2 complete (stream-ordered) before
    // encode_level / encode_dense56 overwrite R0 with staging data.
    const size_t stag_b = (size_t)NSTAGE * (size_t)n * sizeof(f32x2);
    const size_t s1_b   = ((size_t)NCELLS + 256) * sizeof(f32x2);
    const size_t r0_b   = (stag_b > s1_b ? stag_b : s1_b);
    const size_t qoff   = (r0_b + 15) & ~(size_t)15;
    const size_t need   = qoff + (size_t)NCELLS * sizeof(uint4);

    if (ws_size >= need) {
        f32x2* staging = (f32x2*)d_ws;
        f32x2* stage1  = (f32x2*)d_ws;
        uint4* qtab    = (uint4*)((char*)d_ws + qoff);

        const int nbcell = (NCELLS + 255) / 256;
        hipLaunchKernelGGL(remap1_kernel, dim3(nbcell), dim3(256), 0, stream, tables, stage1);
        hipLaunchKernelGGL(remap2_kernel, dim3(nbcell), dim3(256), 0, stream, stage1, qtab);

        const int nb512 = (n + 511) / 512;
        hipLaunchKernelGGL(encode_level_kernel, dim3(nb512 * NHASH), dim3(256), 0, stream,
                           x, tables, staging, n, nb512, HASH0);
        hipLaunchKernelGGL(encode_dense56_kernel, dim3(nb512 * 2), dim3(256), 0, stream,
                           x, qtab, staging, n, nb512);

        const int nb256 = (n + 255) / 256;
        hipLaunchKernelGGL(finalize_kernel, dim3(nb256), dim3(256), 0, stream,
                           x, qtab, staging, out, n);
    } else {
        const int nb = (n + 255) / 256;
        hipLaunchKernelGGL(hashgrid_enc_kernel, dim3(nb), dim3(256), 0, stream,
                           x, tables, out, n);
    }
}

// Round 7
// 936.771 us; speedup vs baseline: 1.0892x; 1.0364x over previous
//
#include <hip/hip_runtime.h>
#include <hip/hip_fp16.h>
#include <stdint.h>

#define LEVELS 16
#define FEAT 2
#define TABLE_SIZE 524288
#define TMASK (TABLE_SIZE - 1)

typedef float f32x2 __attribute__((ext_vector_type(2)));
typedef float f32x4 __attribute__((ext_vector_type(4)));
typedef float f32x4u __attribute__((ext_vector_type(4), aligned(8)));  // 16B load, 8B-aligned ok

__device__ __constant__ int kRes[LEVELS] = {
    16, 22, 30, 42, 58, 80, 111, 153, 212, 294, 406, 561, 775, 1072, 1481, 2047
};

#define P1 73856093u
#define P2 19349663u
#define P3 83492791u

// Quad-packed (fp16) dense tables for levels 0..6. D = res+1.
#define NQ 7
#define NHASH 9                          // hashed levels 7..15
#define NSTAGE (LEVELS - 5)              // 11 staged levels (5..15), slot = level-5 (fp16 half2)
#define NFIN 5                           // finalize-local dense levels 0..4 (L2-resident)

constexpr int   cQD[NQ]     = { 17, 23, 31, 43, 59, 81, 112 };
constexpr float cQRes[NQ]   = { 16.0f, 22.0f, 30.0f, 42.0f, 58.0f, 80.0f, 111.0f };
constexpr int   cQCum[NQ+1] = { 0, 4913, 17080, 46871, 126378, 331757, 863198, 2268126 };
#define NCELLS 2268126                   // total cells across levels 0..6

// ---------------- remap stage 1: hashed tables -> dense f32 [D^3] cells ----------------
__global__ __launch_bounds__(256) void remap1_kernel(
    const float* __restrict__ tables,
    f32x2* __restrict__ dense)           // [NCELLS] (aliases staging region; dead after remap2)
{
    const int d = blockIdx.x * 256 + threadIdx.x;
    if (d >= NCELLS) return;
    int l = 0;
#pragma unroll
    for (int k = 1; k < NQ; ++k)
        if (d >= cQCum[k]) l = k;
    const int D   = cQD[l];
    const int rel = d - cQCum[l];
    const uint32_t bx = rel / (D * D);
    const uint32_t r  = rel - bx * (D * D);
    const uint32_t by = r / D;
    const uint32_t bz = r - by * D;
    const uint32_t slot = ((bx * P1) ^ (by * P2) ^ (bz * P3)) & TMASK;
    const f32x2* __restrict__ tab = reinterpret_cast<const f32x2*>(tables) + (size_t)l * TABLE_SIZE;
    dense[d] = tab[slot];
}

// ---------------- remap stage 2: f32 cells -> fp16 2x2 (y,z) quads, 16B each ----------------
// quad[d] = {c(x,y,z), c(x,y,z+1), c(x,y+1,z), c(x,y+1,z+1)} as 4x half2.
// Quads at y==D-1 / z==D-1 are never read (base coords <= D-2); their overread stays inside
// the (much larger) staging region that stage-1 aliases.
__global__ __launch_bounds__(256) void remap2_kernel(
    const f32x2* __restrict__ dense,
    uint4* __restrict__ qtab)            // [NCELLS]
{
    const int d = blockIdx.x * 256 + threadIdx.x;
    if (d >= NCELLS) return;
    int l = 0;
#pragma unroll
    for (int k = 1; k < NQ; ++k)
        if (d >= cQCum[k]) l = k;
    const int D   = cQD[l];
    const int rel = d - cQCum[l];

    const f32x2* __restrict__ dl = dense + cQCum[l];
    const f32x4u a = *reinterpret_cast<const f32x4u*>(dl + rel);          // (y ,z),(y ,z+1)
    const f32x4u b = *reinterpret_cast<const f32x4u*>(dl + rel + D);      // (y+1,z),(y+1,z+1)

    union { __half2 h; uint32_t u; } p0, p1, p2, p3;
    p0.h = __float22half2_rn(make_float2(a.x, a.y));
    p1.h = __float22half2_rn(make_float2(a.z, a.w));
    p2.h = __float22half2_rn(make_float2(b.x, b.y));
    p3.h = __float22half2_rn(make_float2(b.z, b.w));
    qtab[d] = make_uint4(p0.u, p1.u, p2.u, p3.u);
}

// ---------------- merged encode: hashed levels 7..15 (roles 0..8) + dense L5/L6 (roles 9,10) ----
// Staging is fp16 half2 (4B/point/level), slot = level-5.
__global__ __launch_bounds__(256) void encode_merged_kernel(
    const float* __restrict__ x,
    const float* __restrict__ tables,
    const uint4* __restrict__ qtab,
    uint32_t* __restrict__ ws,
    int n, int nb)
{
    const int role = blockIdx.x / nb;
    const int blk  = blockIdx.x - role * nb;
    const int t    = threadIdx.x;
    const int p0   = blk * 512;

    __shared__ float sx[512 * 3];
    const long long total3 = (long long)n * 3;
    const long long gbase  = (long long)p0 * 3;
#pragma unroll
    for (int k = 0; k < 6; ++k) {
        long long g = gbase + k * 256 + t;
        sx[k * 256 + t] = (g < total3) ? __builtin_nontemporal_load(x + g) : 0.0f;
    }
    __syncthreads();

    if (role < NHASH) {
        // ---- hashed level l = 7 + role (proven 75us/level structure) ----
        const int l = 7 + role;
        const float resf = (float)kRes[l];
        const f32x2* __restrict__ tab = reinterpret_cast<const f32x2*>(tables) + (size_t)l * TABLE_SIZE;

        uint32_t idx[2][8];
        float    wgt[2][8];
#pragma unroll
        for (int s = 0; s < 2; ++s) {
            const int tp = s * 256 + t;
            const float fx = sx[3 * tp + 0] * resf;
            const float fy = sx[3 * tp + 1] * resf;
            const float fz = sx[3 * tp + 2] * resf;
            const float flx = floorf(fx), fly = floorf(fy), flz = floorf(fz);
            const float wx = fx - flx, wy = fy - fly, wz = fz - flz;
            const float ux = 1.0f - wx, uy = 1.0f - wy, uz = 1.0f - wz;
            const uint32_t hx0 = (uint32_t)(int)flx * P1, hx1 = hx0 + P1;
            const uint32_t hy0 = (uint32_t)(int)fly * P2, hy1 = hy0 + P2;
            const uint32_t hz0 = (uint32_t)(int)flz * P3, hz1 = hz0 + P3;
#pragma unroll
            for (int c = 0; c < 8; ++c) {
                const uint32_t hx = (c & 4) ? hx1 : hx0;
                const uint32_t hy = (c & 2) ? hy1 : hy0;
                const uint32_t hz = (c & 1) ? hz1 : hz0;
                idx[s][c] = (hx ^ hy ^ hz) & TMASK;
                wgt[s][c] = ((c & 4) ? wx : ux) * ((c & 2) ? wy : uy) * ((c & 1) ? wz : uz);
            }
        }

        f32x2 v[2][8];
#pragma unroll
        for (int s = 0; s < 2; ++s)
#pragma unroll
            for (int c = 0; c < 8; ++c)
                v[s][c] = tab[idx[s][c]];

#pragma unroll
        for (int s = 0; s < 2; ++s) {
            float f0 = 0.0f, f1 = 0.0f;
#pragma unroll
            for (int c = 0; c < 8; ++c) {
                f0 = fmaf(wgt[s][c], v[s][c].x, f0);
                f1 = fmaf(wgt[s][c], v[s][c].y, f1);
            }
            const int i = p0 + s * 256 + t;
            if (i < n) {
                union { __half2 h; uint32_t u; } r;
                r.h = __floats2half2_rn(f0, f1);
                __builtin_nontemporal_store(r.u, ws + (size_t)(l - 5) * n + i);
            }
        }
    } else {
        // ---- dense level 5 or 6 from fp16 quads (high-MLP structure) ----
        const int lsel = role - NHASH;            // 0 -> level 5, 1 -> level 6
        const int   D    = lsel ? 112 : 81;
        const int   DD   = D * D;
        const float resf = lsel ? 111.0f : 80.0f;
        const uint4* __restrict__ qt = qtab + (lsel ? cQCum[6] : cQCum[5]);

        int   q0a[2];
        float wxa[2], wya[2], wza[2];
#pragma unroll
        for (int s = 0; s < 2; ++s) {
            const int tp = s * 256 + t;
            const float fx = sx[3 * tp + 0] * resf;
            const float fy = sx[3 * tp + 1] * resf;
            const float fz = sx[3 * tp + 2] * resf;
            const float flx = floorf(fx), fly = floorf(fy), flz = floorf(fz);
            wxa[s] = fx - flx; wya[s] = fy - fly; wza[s] = fz - flz;
            q0a[s] = ((int)flx * D + (int)fly) * D + (int)flz;
        }

        uint4 A[2], B[2];
#pragma unroll
        for (int s = 0; s < 2; ++s) {
            A[s] = qt[q0a[s]];
            B[s] = qt[q0a[s] + DD];
        }

#pragma unroll
        for (int s = 0; s < 2; ++s) {
            const float wx = wxa[s], wy = wya[s], wz = wza[s];
            const float ux = 1.0f - wx, uy = 1.0f - wy, uz = 1.0f - wz;

            union { uint32_t u; __half2 hh; } c;
            float2 a00, a01, a10, a11, b00, b01, b10, b11;
            c.u = A[s].x; a00 = __half22float2(c.hh);
            c.u = A[s].y; a01 = __half22float2(c.hh);
            c.u = A[s].z; a10 = __half22float2(c.hh);
            c.u = A[s].w; a11 = __half22float2(c.hh);
            c.u = B[s].x; b00 = __half22float2(c.hh);
            c.u = B[s].y; b01 = __half22float2(c.hh);
            c.u = B[s].z; b10 = __half22float2(c.hh);
            c.u = B[s].w; b11 = __half22float2(c.hh);

            const float ya0 = fmaf(uz, a00.x, wz * a01.x), ya1 = fmaf(uz, a10.x, wz * a11.x);
            const float yb0 = fmaf(uz, b00.x, wz * b01.x), yb1 = fmaf(uz, b10.x, wz * b11.x);
            const float f0  = fmaf(ux, fmaf(uy, ya0, wy * ya1), wx * fmaf(uy, yb0, wy * yb1));
            const float za0 = fmaf(uz, a00.y, wz * a01.y), za1 = fmaf(uz, a10.y, wz * a11.y);
            const float zb0 = fmaf(uz, b00.y, wz * b01.y), zb1 = fmaf(uz, b10.y, wz * b11.y);
            const float f1  = fmaf(ux, fmaf(uy, za0, wy * za1), wx * fmaf(uy, zb0, wy * zb1));

            const int i = p0 + s * 256 + t;
            if (i < n) {
                union { __half2 h; uint32_t u; } r;
                r.h = __floats2half2_rn(f0, f1);
                __builtin_nontemporal_store(r.u, ws + (size_t)lsel * n + i);
            }
        }
    }
}

// ---------------- finalize: 5 L2-resident quad levels + 11 fp16-staged levels + out ----------------
__global__ __launch_bounds__(256) void finalize_kernel(
    const float* __restrict__ x,
    const uint4* __restrict__ qtab,
    const uint32_t* __restrict__ ws,     // fp16 staged, level 5+j at ws + j*n
    float* __restrict__ out,
    int n)
{
    __shared__ float s[256 * 33];
    __shared__ float sx[256 * 3];
    const int t  = threadIdx.x;
    const int p0 = blockIdx.x * 256;
    const int m  = min(256, n - p0);

    const long long total3 = (long long)n * 3;
    const long long gbase  = (long long)p0 * 3;
#pragma unroll
    for (int k = 0; k < 3; ++k) {
        long long g = gbase + k * 256 + t;
        sx[k * 256 + t] = (g < total3) ? __builtin_nontemporal_load(x + g) : 0.0f;
    }
    __syncthreads();

    if (t < m) {
        const int i = p0 + t;

        // staged results: coalesced 4B loads, issued early
        uint32_t h[NSTAGE];
#pragma unroll
        for (int j = 0; j < NSTAGE; ++j)
            h[j] = __builtin_nontemporal_load(ws + (size_t)j * n + i);

        const float px = sx[3 * t + 0];
        const float py = sx[3 * t + 1];
        const float pz = sx[3 * t + 2];

#pragma unroll
        for (int l = 0; l < NFIN; ++l) {
            const int   D    = cQD[l];
            const int   DD   = D * D;
            const float resf = cQRes[l];
            const uint4* __restrict__ qt = qtab + cQCum[l];

            const float fx = px * resf, fy = py * resf, fz = pz * resf;
            const float flx = floorf(fx), fly = floorf(fy), flz = floorf(fz);
            const float wx = fx - flx, wy = fy - fly, wz = fz - flz;
            const float ux = 1.0f - wx, uy = 1.0f - wy, uz = 1.0f - wz;
            const int q0 = (((int)flx * D + (int)fly) * D + (int)flz);

            const uint4 A = qt[q0];        // x = bx  : (y,z),(y,z+1),(y+1,z),(y+1,z+1)
            const uint4 B = qt[q0 + DD];   // x = bx+1

            union { uint32_t u; __half2 hh; } c;
            float2 a00, a01, a10, a11, b00, b01, b10, b11;
            c.u = A.x; a00 = __half22float2(c.hh);
            c.u = A.y; a01 = __half22float2(c.hh);
            c.u = A.z; a10 = __half22float2(c.hh);
            c.u = A.w; a11 = __half22float2(c.hh);
            c.u = B.x; b00 = __half22float2(c.hh);
            c.u = B.y; b01 = __half22float2(c.hh);
            c.u = B.z; b10 = __half22float2(c.hh);
            c.u = B.w; b11 = __half22float2(c.hh);

            const float ya0 = fmaf(uz, a00.x, wz * a01.x), ya1 = fmaf(uz, a10.x, wz * a11.x);
            const float yb0 = fmaf(uz, b00.x, wz * b01.x), yb1 = fmaf(uz, b10.x, wz * b11.x);
            const float f0  = fmaf(ux, fmaf(uy, ya0, wy * ya1), wx * fmaf(uy, yb0, wy * yb1));
            const float za0 = fmaf(uz, a00.y, wz * a01.y), za1 = fmaf(uz, a10.y, wz * a11.y);
            const float zb0 = fmaf(uz, b00.y, wz * b01.y), zb1 = fmaf(uz, b10.y, wz * b11.y);
            const float f1  = fmaf(ux, fmaf(uy, za0, wy * za1), wx * fmaf(uy, zb0, wy * zb1));

            s[t * 33 + 2 * l + 0] = f0;
            s[t * 33 + 2 * l + 1] = f1;
        }
#pragma unroll
        for (int j = 0; j < NSTAGE; ++j) {
            union { uint32_t u; __half2 hh; } c;
            c.u = h[j];
            const float2 hv = __half22float2(c.hh);
            s[t * 33 + 2 * (NFIN + j) + 0] = hv.x;
            s[t * 33 + 2 * (NFIN + j) + 1] = hv.y;
        }
    }
    __syncthreads();

    const int nchunk = m * 8;
    f32x4* __restrict__ o4 = reinterpret_cast<f32x4*>(out) + (size_t)p0 * 8;
#pragma unroll
    for (int j = 0; j < 8; ++j) {
        const int cl = j * 256 + t;
        if (cl < nchunk) {
            const int p = cl >> 3, ch = cl & 7;
            f32x4 q;
            q.x = s[p * 33 + ch * 4 + 0];
            q.y = s[p * 33 + ch * 4 + 1];
            q.z = s[p * 33 + ch * 4 + 2];
            q.w = s[p * 33 + ch * 4 + 3];
            __builtin_nontemporal_store(q, o4 + cl);
        }
    }
}

// ---------------- fallback: fused single-kernel path (if ws too small) ----------------
__global__ __launch_bounds__(256) void hashgrid_enc_kernel(
    const float* __restrict__ x,
    const float* __restrict__ tables,
    float* __restrict__ out,
    int n)
{
    __shared__ float sx[256 * 3];
    const int t = threadIdx.x;
    const int block0 = blockIdx.x * 256;
    const long long total3 = (long long)n * 3;
    const long long gbase = (long long)block0 * 3;
#pragma unroll
    for (int k = 0; k < 3; ++k) {
        long long g = gbase + k * 256 + t;
        sx[k * 256 + t] = (g < total3) ? x[g] : 0.0f;
    }
    __syncthreads();
    const int i = block0 + t;
    if (i >= n) return;
    const float px = sx[3 * t + 0];
    const float py = sx[3 * t + 1];
    const float pz = sx[3 * t + 2];
    float outv[2 * LEVELS];
#pragma unroll
    for (int l = 0; l < LEVELS; ++l) {
        const float resf = (float)kRes[l];
        const float fx = px * resf, fy = py * resf, fz = pz * resf;
        const float flx = floorf(fx), fly = floorf(fy), flz = floorf(fz);
        const float wx = fx - flx, wy = fy - fly, wz = fz - flz;
        const float ux = 1.0f - wx, uy = 1.0f - wy, uz = 1.0f - wz;
        const uint32_t hx0 = (uint32_t)(int)flx * P1, hx1 = hx0 + P1;
        const uint32_t hy0 = (uint32_t)(int)fly * P2, hy1 = hy0 + P2;
        const uint32_t hz0 = (uint32_t)(int)flz * P3, hz1 = hz0 + P3;
        const float* __restrict__ tab = tables + (size_t)l * (TABLE_SIZE * FEAT);
        float f0 = 0.0f, f1 = 0.0f;
#pragma unroll
        for (int c = 0; c < 8; ++c) {
            const uint32_t hx = (c & 4) ? hx1 : hx0;
            const uint32_t hy = (c & 2) ? hy1 : hy0;
            const uint32_t hz = (c & 1) ? hz1 : hz0;
            const uint32_t idx = (hx ^ hy ^ hz) & TMASK;
            const float2 v = *reinterpret_cast<const float2*>(tab + (size_t)idx * FEAT);
            const float w = ((c & 4) ? wx : ux) * ((c & 2) ? wy : uy) * ((c & 1) ? wz : uz);
            f0 = fmaf(w, v.x, f0);
            f1 = fmaf(w, v.y, f1);
        }
        outv[2 * l + 0] = f0;
        outv[2 * l + 1] = f1;
    }
    float4* __restrict__ o4 = reinterpret_cast<float4*>(out + (size_t)i * (2 * LEVELS));
#pragma unroll
    for (int k = 0; k < 8; ++k) {
        o4[k] = make_float4(outv[4 * k + 0], outv[4 * k + 1],
                            outv[4 * k + 2], outv[4 * k + 3]);
    }
}

extern "C" void kernel_launch(void* const* d_in, const int* in_sizes, int n_in,
                              void* d_out, int out_size, void* d_ws, size_t ws_size,
                              hipStream_t stream) {
    const float* x = (const float*)d_in[0];
    const float* tables = (const float*)d_in[1];
    float* out = (float*)d_out;
    const int n = in_sizes[0] / 3;

    // ws layout:
    //   [region R0: max(fp16 staging NSTAGE*n*4B, stage-1 f32 cells (NCELLS+slack)*8B)] [qtab: NCELLS*16B]
    // stage-1 aliases the staging region: remap1/remap2 complete (stream-ordered) before
    // encode_merged overwrites R0 with staging data.
    const size_t stag_b = (size_t)NSTAGE * (size_t)n * sizeof(uint32_t);
    const size_t s1_b   = ((size_t)NCELLS + 256) * sizeof(f32x2);
    const size_t r0_b   = (stag_b > s1_b ? stag_b : s1_b);
    const size_t qoff   = (r0_b + 15) & ~(size_t)15;
    const size_t need   = qoff + (size_t)NCELLS * sizeof(uint4);

    if (ws_size >= need) {
        uint32_t* staging = (uint32_t*)d_ws;
        f32x2*    stage1  = (f32x2*)d_ws;
        uint4*    qtab    = (uint4*)((char*)d_ws + qoff);

        const int nbcell = (NCELLS + 255) / 256;
        hipLaunchKernelGGL(remap1_kernel, dim3(nbcell), dim3(256), 0, stream, tables, stage1);
        hipLaunchKernelGGL(remap2_kernel, dim3(nbcell), dim3(256), 0, stream, stage1, qtab);

        const int nb512 = (n + 511) / 512;
        hipLaunchKernelGGL(encode_merged_kernel, dim3(nb512 * (NHASH + 2)), dim3(256), 0, stream,
                           x, tables, qtab, staging, n, nb512);

        const int nb256 = (n + 255) / 256;
        hipLaunchKernelGGL(finalize_kernel, dim3(nb256), dim3(256), 0, stream,
                           x, qtab, staging, out, n);
    } else {
        const int nb = (n + 255) / 256;
        hipLaunchKernelGGL(hashgrid_enc_kernel, dim3(nb), dim3(256), 0, stream,
                           x, tables, out, n);
    }
}